// Round 1
// baseline (444.913 us; speedup 1.0000x reference)
//
#include <hip/hip_runtime.h>

#define DIM 1024
#define HEADS 16
#define DHEAD 64
#define SEQ 2048
#define BATCH 4
#define ROWS (BATCH*SEQ)        // 8192
#define QK_COLS (3*DIM)         // 3072
// SCALE * log2(e) folded into Q so softmax runs in base-2 space (identical result)
#define QSCALE 0.18033688011112042f

typedef __bf16 bf16x8 __attribute__((ext_vector_type(8)));
typedef float f32x4 __attribute__((ext_vector_type(4)));
typedef unsigned short u16;
typedef unsigned int u32;

__device__ __forceinline__ u16 f2bf(float f) {
  u32 u = __float_as_uint(f);
  u = (u + 0x7fffu + ((u >> 16) & 1u)) >> 16;
  return (u16)u;
}

__device__ __forceinline__ void gld16(const void* g, void* s) {
  __builtin_amdgcn_global_load_lds((__attribute__((address_space(1))) void*)g,
                                   (__attribute__((address_space(3))) void*)s, 16, 0, 0);
}

// ---------------- LayerNorm: fp32 in -> bf16 out ----------------
__global__ __launch_bounds__(256) void ln_kernel(const float* __restrict__ x,
    const float* __restrict__ gam, const float* __restrict__ bet, u16* __restrict__ xn) {
  int row = blockIdx.x, tid = threadIdx.x;
  int lane = tid & 63, w = tid >> 6;
  const float4 xv = *(const float4*)(x + (size_t)row*DIM + tid*4);
  float s = xv.x + xv.y + xv.z + xv.w;
  float q = xv.x*xv.x + xv.y*xv.y + xv.z*xv.z + xv.w*xv.w;
  for (int off = 32; off > 0; off >>= 1) { s += __shfl_xor(s, off, 64); q += __shfl_xor(q, off, 64); }
  __shared__ float red[8];
  if (lane == 0) { red[w] = s; red[4+w] = q; }
  __syncthreads();
  s = red[0]+red[1]+red[2]+red[3];
  q = red[4]+red[5]+red[6]+red[7];
  float mean = s * (1.0f/DIM);
  float rstd = rsqrtf(q*(1.0f/DIM) - mean*mean + 1e-5f);
  float4 gv = *(const float4*)(gam + tid*4);
  float4 bv = *(const float4*)(bet + tid*4);
  ushort4 o;
  o.x = f2bf((xv.x-mean)*rstd*gv.x + bv.x);
  o.y = f2bf((xv.y-mean)*rstd*gv.y + bv.y);
  o.z = f2bf((xv.z-mean)*rstd*gv.z + bv.z);
  o.w = f2bf((xv.w-mean)*rstd*gv.w + bv.w);
  *(ushort4*)(xn + (size_t)row*DIM + tid*4) = o;
}

// ------------- weight transpose fp32[R][C] -> bf16[C][R] -------------
__global__ __launch_bounds__(256) void transpose_w(const float* __restrict__ in,
    u16* __restrict__ out, int R, int C) {
  __shared__ float tile[32][33];
  int c0 = blockIdx.x * 32, r0 = blockIdx.y * 32;
  int tx = threadIdx.x & 31, ty = threadIdx.x >> 5;
  for (int i = 0; i < 32; i += 8)
    tile[ty+i][tx] = in[(size_t)(r0+ty+i)*C + c0 + tx];
  __syncthreads();
  for (int i = 0; i < 32; i += 8)
    out[(size_t)(c0+ty+i)*R + r0 + tx] = f2bf(tile[tx][ty+i]);
}

// ------- V transpose: qkv V-region [n][h*64+d] -> vT[bh][d][j] with chunk swizzle -------
__global__ __launch_bounds__(256) void transpose_v(const u16* __restrict__ qkv, u16* __restrict__ vT) {
  __shared__ u16 tile[64][66];
  int nt = blockIdx.x, bh = blockIdx.y;
  int b = bh >> 4, h = bh & 15;
  int n0 = nt * 64;
  int tx = threadIdx.x & 31, ty = threadIdx.x >> 5;
  for (int i = 0; i < 64; i += 8) {
    int n = i + ty;
    ushort2 v = *(const ushort2*)(qkv + (size_t)(b*SEQ + n0 + n)*QK_COLS + 2*DIM + h*DHEAD + tx*2);
    tile[n][tx*2] = v.x; tile[n][tx*2+1] = v.y;
  }
  __syncthreads();
  for (int i = 0; i < 64; i += 8) {
    int d = i + ty;
    int c2 = tx*2;
    int jg = n0 + c2;
    int cj = (jg >> 3) & 15;
    int dest = (jg & ~127) | ((cj ^ (d & 15)) << 3) | (jg & 7);
    ushort2 v; v.x = tile[c2][d]; v.y = tile[c2+1][d];
    *(ushort2*)(vT + ((size_t)bh*DHEAD + d)*SEQ + dest) = v;
  }
}

// ---------------- GEMM: C = A[M][K] * Bt[N][K]^T, 128x128 tile, BK=32 ----------------
// EPI 0: write bf16 qkv (scale Q cols by QSCALE, chunk-swizzle K cols on seq&7)
// EPI 1: write fp32 C[M][NOUT]
template<int NOUT, int EPI>
__global__ __launch_bounds__(256, 2) void gemm_bt(const u16* __restrict__ A, const u16* __restrict__ Bt,
                                                  void* __restrict__ Cv, int K) {
  __shared__ alignas(16) u16 As[128*32];
  __shared__ alignas(16) u16 Bs[128*32];
  int tid = threadIdx.x;
  int lane = tid & 63, w = tid >> 6;
  int l = lane & 15, quad = lane >> 4;
  int wm = (w & 1) * 64, wn = (w >> 1) * 64;
  int m0 = blockIdx.y * 128, n0 = blockIdx.x * 128;
  const u16* Ag = A + (size_t)m0 * K;
  const u16* Bg = Bt + (size_t)n0 * K;
  f32x4 z = {0.f, 0.f, 0.f, 0.f};
  f32x4 acc[4][4];
  for (int i = 0; i < 4; ++i) for (int j = 0; j < 4; ++j) acc[i][j] = z;
  for (int kt = 0; kt < K; kt += 32) {
    __syncthreads();
    for (int c = 0; c < 2; ++c) {
      int idx = c*256 + tid;
      int row = idx >> 2, col = (idx & 3) << 3;
      gld16(Ag + (size_t)row*K + kt + col, (u16*)As + idx*8);
      gld16(Bg + (size_t)row*K + kt + col, (u16*)Bs + idx*8);
    }
    __syncthreads();
    bf16x8 af[4], bfr[4];
    for (int t = 0; t < 4; ++t) {
      af[t]  = *(const bf16x8*)(As + (wm + t*16 + l)*32 + quad*8);
      bfr[t] = *(const bf16x8*)(Bs + (wn + t*16 + l)*32 + quad*8);
    }
    for (int i = 0; i < 4; ++i)
      for (int j = 0; j < 4; ++j)
        acc[i][j] = __builtin_amdgcn_mfma_f32_16x16x32_bf16(af[i], bfr[j], acc[i][j], 0, 0, 0);
  }
  if (EPI == 0) {
    u16* C = (u16*)Cv;
    int region = n0 >> 10;  // 0=Q, 1=K, 2=V; 128-wide block never straddles
    for (int i = 0; i < 4; ++i)
      for (int j = 0; j < 4; ++j)
        for (int r = 0; r < 4; ++r) {
          int mg = m0 + wm + i*16 + quad*4 + r;
          int ng = n0 + wn + j*16 + l;
          float v = acc[i][j][r];
          int col = ng;
          if (region == 0) v *= QSCALE;
          else if (region == 1) {
            int d = ng & 63;
            col = (ng & ~63) | ((((d >> 3) ^ (mg & 7)) << 3) | (d & 7));
          }
          C[(size_t)mg * QK_COLS + col] = f2bf(v);
        }
  } else {
    float* C = (float*)Cv;
    for (int i = 0; i < 4; ++i)
      for (int j = 0; j < 4; ++j)
        for (int r = 0; r < 4; ++r) {
          int mg = m0 + wm + i*16 + quad*4 + r;
          int ng = n0 + wn + j*16 + l;
          C[(size_t)mg * NOUT + ng] = acc[i][j][r];
        }
  }
}

// ---------------- Flash attention: one (b,h), 128 Q rows per block ----------------
__global__ __launch_bounds__(256, 2) void attn_kernel(const u16* __restrict__ qkv,
    const u16* __restrict__ vT, u16* __restrict__ aout) {
  __shared__ alignas(16) u16 Kt[128*64];   // [j][d-chunk-swizzled]
  __shared__ alignas(16) u16 Vt[64*128];   // [d][j-chunk-swizzled]
  __shared__ alignas(16) u16 Pt[128*128];  // wave-local strips, C-layout -> A-layout
  int tid = threadIdx.x;
  int lane = tid & 63, w = tid >> 6;
  int l = lane & 15, quad = lane >> 4;
  int qt = blockIdx.x, bh = blockIdx.y;
  int b = bh >> 4, h = bh & 15;
  int qrow0 = b*SEQ + qt*128;

  bf16x8 aq[2][2];
  for (int mt = 0; mt < 2; ++mt)
    for (int ks = 0; ks < 2; ++ks) {
      int m = w*32 + mt*16 + l;
      aq[mt][ks] = *(const bf16x8*)(qkv + (size_t)(qrow0 + m)*QK_COLS + h*DHEAD + ks*32 + quad*8);
    }
  f32x4 z = {0.f,0.f,0.f,0.f};
  f32x4 o[2][4];
  for (int i = 0; i < 2; ++i) for (int j = 0; j < 4; ++j) o[i][j] = z;
  float mi[2][4], li[2][4];
  for (int i = 0; i < 2; ++i) for (int r = 0; r < 4; ++r) { mi[i][r] = -1e30f; li[i][r] = 0.f; }

  for (int kt = 0; kt < 16; ++kt) {
    __syncthreads();
    int krow0 = kt*128;
    for (int c = 0; c < 4; ++c) {
      int idx = c*256 + tid;
      int r  = idx >> 3, ccol = (idx & 7) << 3;
      gld16(qkv + (size_t)(b*SEQ + krow0 + r)*QK_COLS + DIM + h*DHEAD + ccol, (u16*)Kt + idx*8);
      int r2 = idx >> 4, col2 = (idx & 15) << 3;
      gld16(vT + ((size_t)bh*DHEAD + r2)*SEQ + krow0 + col2, (u16*)Vt + idx*8);
    }
    __syncthreads();
    // S = Q K^T (pre-scaled base-2 logits)
    f32x4 s[2][8];
    for (int a = 0; a < 2; ++a) for (int nj = 0; nj < 8; ++nj) s[a][nj] = z;
    for (int nj = 0; nj < 8; ++nj) {
      int jl = nj*16 + l;
      for (int ks = 0; ks < 2; ++ks) {
        bf16x8 bk = *(const bf16x8*)(Kt + jl*64 + (((ks*4 + quad) ^ (jl & 7)) << 3));
        s[0][nj] = __builtin_amdgcn_mfma_f32_16x16x32_bf16(aq[0][ks], bk, s[0][nj], 0,0,0);
        s[1][nj] = __builtin_amdgcn_mfma_f32_16x16x32_bf16(aq[1][ks], bk, s[1][nj], 0,0,0);
      }
    }
    // online softmax (rows live in C-layout: row = mt*16 + quad*4 + r)
    for (int mt = 0; mt < 2; ++mt)
      for (int r = 0; r < 4; ++r) {
        float vm = s[mt][0][r];
        for (int nj = 1; nj < 8; ++nj) vm = fmaxf(vm, s[mt][nj][r]);
        for (int off = 1; off < 16; off <<= 1) vm = fmaxf(vm, __shfl_xor(vm, off, 64));
        float mnew = fmaxf(mi[mt][r], vm);
        float alpha = exp2f(mi[mt][r] - mnew);
        mi[mt][r] = mnew;
        float ps = 0.f;
        for (int nj = 0; nj < 8; ++nj) {
          float p = exp2f(s[mt][nj][r] - mnew);
          s[mt][nj][r] = p;
          ps += p;
        }
        for (int off = 1; off < 16; off <<= 1) ps += __shfl_xor(ps, off, 64);
        li[mt][r] = li[mt][r]*alpha + ps;
        for (int nd = 0; nd < 4; ++nd) o[mt][nd][r] *= alpha;
      }
    // P (bf16) -> LDS, wave-local strip
    for (int mt = 0; mt < 2; ++mt)
      for (int nj = 0; nj < 8; ++nj)
        for (int r = 0; r < 4; ++r)
          Pt[(w*32 + mt*16 + quad*4 + r)*128 + nj*16 + l] = f2bf(s[mt][nj][r]);
    __asm__ volatile("s_waitcnt lgkmcnt(0)" ::: "memory");
    // O += P * V
    for (int k2 = 0; k2 < 4; ++k2) {
      bf16x8 ap0 = *(const bf16x8*)(Pt + (w*32 +      l)*128 + k2*32 + quad*8);
      bf16x8 ap1 = *(const bf16x8*)(Pt + (w*32 + 16 + l)*128 + k2*32 + quad*8);
      for (int nd = 0; nd < 4; ++nd) {
        int dl = nd*16 + l;
        bf16x8 bv = *(const bf16x8*)(Vt + dl*128 + (((k2*4 + quad) ^ l) << 3));
        o[0][nd] = __builtin_amdgcn_mfma_f32_16x16x32_bf16(ap0, bv, o[0][nd], 0,0,0);
        o[1][nd] = __builtin_amdgcn_mfma_f32_16x16x32_bf16(ap1, bv, o[1][nd], 0,0,0);
      }
    }
  }
  for (int mt = 0; mt < 2; ++mt)
    for (int r = 0; r < 4; ++r) {
      float inv = 1.0f / li[mt][r];
      for (int nd = 0; nd < 4; ++nd) {
        int row = qrow0 + w*32 + mt*16 + quad*4 + r;
        int col = h*DHEAD + nd*16 + l;
        aout[(size_t)row*DIM + col] = f2bf(o[mt][nd][r] * inv);
      }
    }
}

extern "C" void kernel_launch(void* const* d_in, const int* in_sizes, int n_in,
                              void* d_out, int out_size, void* d_ws, size_t ws_size,
                              hipStream_t stream) {
  const float* x    = (const float*)d_in[0];
  const float* gam  = (const float*)d_in[1];
  const float* bet  = (const float*)d_in[2];
  const float* wqkv = (const float*)d_in[3];
  const float* wout = (const float*)d_in[4];
  float* out = (float*)d_out;

  // workspace layout (bf16 elements), total ~104 MB
  u16* xn    = (u16*)d_ws;                          // 8192*1024
  u16* wqkvT = xn    + (size_t)ROWS*DIM;            // 3072*1024  [N][K]
  u16* woutT = wqkvT + (size_t)QK_COLS*DIM;         // 1024*1024  [N][K]
  u16* qkvb  = woutT + (size_t)DIM*DIM;             // 8192*3072  (Q scaled, K swizzled)
  u16* vTb   = qkvb  + (size_t)ROWS*QK_COLS;        // 64*64*2048 V^T per (b,h), swizzled
  u16* aoutb = vTb   + (size_t)64*DHEAD*SEQ;        // 8192*1024

  ln_kernel<<<ROWS, 256, 0, stream>>>(x, gam, bet, xn);
  transpose_w<<<dim3(QK_COLS/32, DIM/32), 256, 0, stream>>>(wqkv, wqkvT, DIM, QK_COLS);
  transpose_w<<<dim3(DIM/32, DIM/32), 256, 0, stream>>>(wout, woutT, DIM, DIM);
  gemm_bt<QK_COLS,0><<<dim3(QK_COLS/128, ROWS/128), 256, 0, stream>>>(xn, wqkvT, (void*)qkvb, DIM);
  transpose_v<<<dim3(SEQ/64, 64), 256, 0, stream>>>(qkvb, vTb);
  attn_kernel<<<dim3(SEQ/128, 64), 256, 0, stream>>>(qkvb, vTb, aoutb);
  gemm_bt<DIM,1><<<dim3(DIM/128, ROWS/128), 256, 0, stream>>>(aoutb, woutT, (void*)out, DIM);
}